// Round 9
// baseline (136.381 us; speedup 1.0000x reference)
//
#include <hip/hip_runtime.h>
#include <math.h>

// Problem constants: B=8, L=512, H=512, NH=8, DH=64
#define Bn 8
#define Ln 512
#define Hn 512
#define NHn 8
#define DHn 64

typedef __attribute__((ext_vector_type(8))) short short8;
typedef __attribute__((ext_vector_type(4))) float f32x4;

// fp32 -> bf16 (RNE)
__device__ __forceinline__ unsigned short f2bf(float f) {
    unsigned int u = __float_as_uint(f);
    unsigned int r = (u + 0x7FFFu + ((u >> 16) & 1u)) >> 16;
    return (unsigned short)r;
}
__device__ __forceinline__ float bf2f(unsigned short s) {
    return __uint_as_float(((unsigned int)s) << 16);
}
// pack 4 fp32 -> 4 bf16 (2 dwords)
__device__ __forceinline__ uint2 pack4(float4 v) {
    uint2 r;
    r.x = (unsigned)f2bf(v.x) | ((unsigned)f2bf(v.y) << 16);
    r.y = (unsigned)f2bf(v.z) | ((unsigned)f2bf(v.w) << 16);
    return r;
}

// ---------------------------------------------------------------------------
// Kernel 1: fused projection GEMMs, fp32 inputs -> bf16 outputs, conversion
// folded into register-prefetch staging (tile k+1 fp32 loads issue after the
// staging barrier and retire under tile k's ds_reads + 16 MFMAs).
// 128x128 tile, BK=32, 256 threads (2x2 waves, 64x64 each). Flat 416 grid:
//  bid <256 : QK[m][n]   = src.W{q,k}_n + b{q,k}[n]   (M=4096, N=1024)
//  bid <384 : VT[dv][j'] = Wv_dv.src_j' + bv[dv]      (swap -> C-layout
//             directly yields V^T [512][4096], coalesced)
//  else     : Rp[m][n]   = pe.Wr_n + br[n]            (M=1024, N=512)
// ---------------------------------------------------------------------------
__global__ __launch_bounds__(256) void gemm_kernel(
    const float* __restrict__ src, const float* __restrict__ pe,
    const float* __restrict__ Wq, const float* __restrict__ Wk,
    const float* __restrict__ Wv, const float* __restrict__ Wr,
    const float* __restrict__ bq, const float* __restrict__ bk,
    const float* __restrict__ bv, const float* __restrict__ br,
    unsigned short* __restrict__ QKb,   // [4096][1024]
    unsigned short* __restrict__ VTg,   // [512][4096]
    unsigned short* __restrict__ Rpb)   // [1024][512]
{
    const int bid = blockIdx.x;
    int mode, m0, n0;
    const float *A, *B;
    if (bid < 256) {
        mode = 0; n0 = (bid & 7) * 128; m0 = (bid >> 3) * 128;
        A = src + (size_t)m0 * 512;
        B = (n0 < 512) ? (Wq + (size_t)n0 * 512) : (Wk + (size_t)(n0 - 512) * 512);
    } else if (bid < 384) {
        mode = 1; m0 = ((bid - 256) & 3) * 128; n0 = ((bid - 256) >> 2) * 128;
        A = Wv + (size_t)m0 * 512;
        B = src + (size_t)n0 * 512;
    } else {
        mode = 2; n0 = ((bid - 384) & 3) * 128; m0 = ((bid - 384) >> 2) * 128;
        A = pe + (size_t)m0 * 512;
        B = Wr + (size_t)n0 * 512;
    }

    __shared__ unsigned short As[128 * 32];
    __shared__ unsigned short Bs[128 * 32];

    const int t = threadIdx.x;
    const int wave = t >> 6, lane = t & 63;
    const int wm = (wave >> 1) * 64;
    const int wn = (wave & 1) * 64;

    f32x4 acc[4][4] = {};

    const int srow = wave * 32 + (lane >> 2);   // rows srow and srow+16
    const int scol = (lane & 3) * 8;            // 8 elems per row-half
    const float* Ag = A + (size_t)srow * 512 + scol;
    const float* Bg = B + (size_t)srow * 512 + scol;
    unsigned short* AsW = &As[srow * 32 + scol];
    unsigned short* BsW = &Bs[srow * 32 + scol];

    // prologue prefetch (tile 0), fp32
    float4 a00 = *(const float4*)(Ag);
    float4 a01 = *(const float4*)(Ag + 4);
    float4 a10 = *(const float4*)(Ag + 16 * 512);
    float4 a11 = *(const float4*)(Ag + 16 * 512 + 4);
    float4 b00 = *(const float4*)(Bg);
    float4 b01 = *(const float4*)(Bg + 4);
    float4 b10 = *(const float4*)(Bg + 16 * 512);
    float4 b11 = *(const float4*)(Bg + 16 * 512 + 4);

    for (int k0 = 0; k0 < 512; k0 += 32) {
        __syncthreads();   // prev-iter fragment reads done before overwrite
        {
            uint2 al0 = pack4(a00), al1 = pack4(a01);
            uint2 ah0 = pack4(a10), ah1 = pack4(a11);
            uint2 bl0 = pack4(b00), bl1 = pack4(b01);
            uint2 bh0 = pack4(b10), bh1 = pack4(b11);
            *(uint4*)(AsW)           = make_uint4(al0.x, al0.y, al1.x, al1.y);
            *(uint4*)(AsW + 16 * 32) = make_uint4(ah0.x, ah0.y, ah1.x, ah1.y);
            *(uint4*)(BsW)           = make_uint4(bl0.x, bl0.y, bl1.x, bl1.y);
            *(uint4*)(BsW + 16 * 32) = make_uint4(bh0.x, bh0.y, bh1.x, bh1.y);
        }
        __syncthreads();

        // prefetch tile k+1 (fp32; retires under the ds_reads + MFMAs below)
        if (k0 + 32 < 512) {
            const int kn = k0 + 32;
            a00 = *(const float4*)(Ag + kn);
            a01 = *(const float4*)(Ag + kn + 4);
            a10 = *(const float4*)(Ag + kn + 16 * 512);
            a11 = *(const float4*)(Ag + kn + 16 * 512 + 4);
            b00 = *(const float4*)(Bg + kn);
            b01 = *(const float4*)(Bg + kn + 4);
            b10 = *(const float4*)(Bg + kn + 16 * 512);
            b11 = *(const float4*)(Bg + kn + 16 * 512 + 4);
        }

        short8 af[4], bf[4];
        #pragma unroll
        for (int mt = 0; mt < 4; ++mt)
            af[mt] = *(const short8*)&As[(wm + mt * 16 + (lane & 15)) * 32 + (lane >> 4) * 8];
        #pragma unroll
        for (int nt = 0; nt < 4; ++nt)
            bf[nt] = *(const short8*)&Bs[(wn + nt * 16 + (lane & 15)) * 32 + (lane >> 4) * 8];
        #pragma unroll
        for (int mt = 0; mt < 4; ++mt)
            #pragma unroll
            for (int nt = 0; nt < 4; ++nt)
                acc[mt][nt] = __builtin_amdgcn_mfma_f32_16x16x32_bf16(
                    af[mt], bf[nt], acc[mt][nt], 0, 0, 0);
    }

    const int crow = (lane >> 4) * 4;
    const int ccol = lane & 15;
    if (mode == 0) {
        #pragma unroll
        for (int mt = 0; mt < 4; ++mt)
            #pragma unroll
            for (int nt = 0; nt < 4; ++nt) {
                const int n = n0 + wn + nt * 16 + ccol;
                const float bn = (n < 512) ? bq[n] : bk[n - 512];
                #pragma unroll
                for (int r = 0; r < 4; ++r) {
                    const int m = m0 + wm + mt * 16 + crow + r;
                    QKb[(size_t)m * 1024 + n] = f2bf(acc[mt][nt][r] + bn);
                }
            }
    } else if (mode == 1) {
        #pragma unroll
        for (int mt = 0; mt < 4; ++mt)
            #pragma unroll
            for (int nt = 0; nt < 4; ++nt) {
                const int n = n0 + wn + nt * 16 + ccol;      // src row (j')
                #pragma unroll
                for (int r = 0; r < 4; ++r) {
                    const int dv = m0 + wm + mt * 16 + crow + r;  // 0..511
                    VTg[(size_t)dv * 4096 + n] = f2bf(acc[mt][nt][r] + bv[dv]);
                }
            }
    } else {
        #pragma unroll
        for (int mt = 0; mt < 4; ++mt)
            #pragma unroll
            for (int nt = 0; nt < 4; ++nt) {
                const int n = n0 + wn + nt * 16 + ccol;
                const float bn = br[n];
                #pragma unroll
                for (int r = 0; r < 4; ++r) {
                    const int m = m0 + wm + mt * 16 + crow + r;
                    Rpb[(size_t)m * 512 + n] = f2bf(acc[mt][nt][r] + bn);
                }
            }
    }
}

// ---------------------------------------------------------------------------
// Kernel 2: fused flash-style rel-pos attention, bf16 MFMA, rolling Bt band,
// register prefetch, masked-tile skip (j0 >= seq_len tiles contribute exactly
// zero -> skipped; block-uniform branch). Block = (b,h,64-row i-tile).
// ---------------------------------------------------------------------------
#define PADK 72    // LDS row stride for k/v/rs/p tiles (ushorts)
__global__ __launch_bounds__(256) void attn_kernel(
    const unsigned short* __restrict__ QKb,  // [4096][1024] bf16: q|k
    const unsigned short* __restrict__ VTg,  // [512][4096] bf16 V^T
    const unsigned short* __restrict__ Rpb,  // [1024][512] bf16
    const float* __restrict__ u, const float* __restrict__ v,
    const int* __restrict__ seq_len, unsigned short* __restrict__ Ob)
{
    const int i0 = blockIdx.x * 64;
    const int h  = blockIdx.y;
    const int b  = blockIdx.z;
    const int slen = seq_len[b];
    const int njt = (slen + 63) >> 6;   // 4..8 tiles with any unmasked key

    __shared__ unsigned short k_s [64 * PADK];    // 9216 B
    __shared__ unsigned short vT_s[64 * PADK];    // 9216 B
    __shared__ unsigned short rs_s[64 * PADK];    // 9216 B
    __shared__ unsigned short p_s [64 * PADK];    // 9216 B
    __shared__ unsigned short qrTT[128 * 72];     // 18432 B  QR^T[slot][i]
    // total 55,296 B -> 2 blocks/CU

    const int t = threadIdx.x;
    const int wave = t >> 6, lane = t & 63;
    const int l = lane & 15, g = lane >> 4;

    // ---- per-wave A-fragments qu=q+u, qv=q+v (registers, whole j-loop) ----
    short8 af_qu[2], af_qv[2];
    {
        const unsigned short* qrow =
            QKb + (size_t)(b * 512 + i0 + wave * 16 + l) * 1024 + h * 64;
        #pragma unroll
        for (int kk = 0; kk < 2; ++kk) {
            const int c = kk * 32 + g * 8;
            unsigned short q8[8];
            *(uint4*)q8 = *(const uint4*)(qrow + c);
            float4 u0 = *(const float4*)(u + h * 64 + c);
            float4 u1 = *(const float4*)(u + h * 64 + c + 4);
            float4 v0 = *(const float4*)(v + h * 64 + c);
            float4 v1 = *(const float4*)(v + h * 64 + c + 4);
            float uf[8] = {u0.x,u0.y,u0.z,u0.w,u1.x,u1.y,u1.z,u1.w};
            float vf[8] = {v0.x,v0.y,v0.z,v0.w,v1.x,v1.y,v1.z,v1.w};
            short8 qu, qv;
            #pragma unroll
            for (int e = 0; e < 8; ++e) {
                float qf = bf2f(q8[e]);
                qu[e] = (short)f2bf(qf + uf[e]);
                qv[e] = (short)f2bf(qf + vf[e]);
            }
            af_qu[kk] = qu; af_qv[kk] = qv;
        }
    }

    float m_run[4], l_run[4];
    f32x4 accO[4] = {};
    #pragma unroll
    for (int r = 0; r < 4; ++r) { m_run[r] = -3.0e38f; l_run[r] = 0.f; }

    const int jr = t >> 2, c0 = (t & 3) * 16;   // staging coords

    auto btChunk = [&](int slot0) {
        #pragma unroll
        for (int nt8 = 0; nt8 < 4; ++nt8) {
            f32x4 a = {};
            #pragma unroll
            for (int kk = 0; kk < 2; ++kk) {
                short8 br8 = *(const short8*)&rs_s[(nt8 * 16 + l) * PADK + kk * 32 + g * 8];
                a = __builtin_amdgcn_mfma_f32_16x16x32_bf16(af_qv[kk], br8, a, 0, 0, 0);
            }
            const int sl = slot0 + nt8 * 16 + l;   // slot0 in {0,64} -> sl in [0,127]
            ushort4 w4;
            w4.x = f2bf(a[0]); w4.y = f2bf(a[1]); w4.z = f2bf(a[2]); w4.w = f2bf(a[3]);
            *(ushort4*)(qrTT + sl * 72 + wave * 16 + g * 4) = w4;   // 4 consecutive i
        }
    };

    // ---- prefetch chunk-A rs + tile-0 K/V/rs into registers ----
    const unsigned short* rpA = Rpb + (size_t)(448 - i0 + jr) * 512 + h * 64 + c0;
    uint4 rA0 = *(const uint4*)(rpA);
    uint4 rA1 = *(const uint4*)(rpA + 8);
    const unsigned short* kp0 = QKb + (size_t)(b * 512 + jr) * 1024 + 512 + h * 64 + c0;
    uint4 kc0 = *(const uint4*)(kp0), kc1 = *(const uint4*)(kp0 + 8);
    const unsigned short* vp0 = VTg + (size_t)(h * 64 + jr) * 4096 + b * 512 + c0;
    uint4 vc0 = *(const uint4*)(vp0), vc1 = *(const uint4*)(vp0 + 8);
    const unsigned short* rp0 = Rpb + (size_t)(512 - i0 + jr) * 512 + h * 64 + c0;
    uint4 rc0 = *(const uint4*)(rp0), rc1 = *(const uint4*)(rp0 + 8);

    // ---- chunk A: stage + Bt for bands [448-i0, 512-i0) ----
    *(uint4*)(rs_s + jr * PADK + c0)     = rA0;
    *(uint4*)(rs_s + jr * PADK + c0 + 8) = rA1;
    __syncthreads();
    btChunk((448 - i0) & 127);

    for (int jt = 0; jt < njt; ++jt) {
        const int j0 = jt * 64;
        __syncthreads();   // all prior LDS reads done before restaging

        *(uint4*)(k_s  + jr * PADK + c0)     = kc0;
        *(uint4*)(k_s  + jr * PADK + c0 + 8) = kc1;
        *(uint4*)(vT_s + jr * PADK + c0)     = vc0;
        *(uint4*)(vT_s + jr * PADK + c0 + 8) = vc1;
        *(uint4*)(rs_s + jr * PADK + c0)     = rc0;
        *(uint4*)(rs_s + jr * PADK + c0 + 8) = rc1;
        __syncthreads();

        // prefetch next tile's globals (retire during compute below)
        if (jt + 1 < njt) {
            const unsigned short* kp =
                QKb + (size_t)(b * 512 + j0 + 64 + jr) * 1024 + 512 + h * 64 + c0;
            kc0 = *(const uint4*)(kp); kc1 = *(const uint4*)(kp + 8);
            const unsigned short* vp =
                VTg + (size_t)(h * 64 + jr) * 4096 + b * 512 + j0 + 64 + c0;
            vc0 = *(const uint4*)(vp); vc1 = *(const uint4*)(vp + 8);
            const unsigned short* rp =
                Rpb + (size_t)(j0 + 64 - i0 + 512 + jr) * 512 + h * 64 + c0;
            rc0 = *(const uint4*)(rp); rc1 = *(const uint4*)(rp + 8);
        }

        // Bt: new bands for this tile
        btChunk((j0 - i0 + 512) & 127);

        // A-term: accA[nt] = qu . K^T
        f32x4 accA[4];
        #pragma unroll
        for (int nt = 0; nt < 4; ++nt) {
            f32x4 a = {};
            #pragma unroll
            for (int kk = 0; kk < 2; ++kk) {
                short8 bk8 = *(const short8*)&k_s[(nt * 16 + l) * PADK + kk * 32 + g * 8];
                a = __builtin_amdgcn_mfma_f32_16x16x32_bf16(af_qu[kk], bk8, a, 0, 0, 0);
            }
            accA[nt] = a;
        }

        // gather rolling band + scale + mask
        float sv[4][4];
        #pragma unroll
        for (int nt = 0; nt < 4; ++nt)
            #pragma unroll
            for (int r = 0; r < 4; ++r) {
                const int il = wave * 16 + g * 4 + r;
                const int slot = (j0 + nt * 16 + l - i0 - il + 512) & 127;
                const float qr = bf2f(qrTT[slot * 72 + il]);
                float s = (accA[nt][r] + qr) * 0.125f;
                if (j0 + nt * 16 + l >= slen) s = -1e15f;
                sv[nt][r] = s;
            }

        // online softmax (row r owned by lanes sharing g)
        float alpha_r[4];
        #pragma unroll
        for (int r = 0; r < 4; ++r) {
            float tm = fmaxf(fmaxf(sv[0][r], sv[1][r]), fmaxf(sv[2][r], sv[3][r]));
            tm = fmaxf(tm, __shfl_xor(tm, 1, 64));
            tm = fmaxf(tm, __shfl_xor(tm, 2, 64));
            tm = fmaxf(tm, __shfl_xor(tm, 4, 64));
            tm = fmaxf(tm, __shfl_xor(tm, 8, 64));
            const float mn = fmaxf(m_run[r], tm);
            alpha_r[r] = __expf(m_run[r] - mn);
            m_run[r] = mn;
            float ss = 0.f;
            #pragma unroll
            for (int nt = 0; nt < 4; ++nt) {
                const float pe_ = __expf(sv[nt][r] - mn);
                sv[nt][r] = pe_; ss += pe_;
            }
            ss += __shfl_xor(ss, 1, 64);
            ss += __shfl_xor(ss, 2, 64);
            ss += __shfl_xor(ss, 4, 64);
            ss += __shfl_xor(ss, 8, 64);
            l_run[r] = l_run[r] * alpha_r[r] + ss;
        }

        // write P (wave-private 16-row region)
        #pragma unroll
        for (int nt = 0; nt < 4; ++nt)
            #pragma unroll
            for (int r = 0; r < 4; ++r)
                p_s[(wave * 16 + g * 4 + r) * PADK + nt * 16 + l] = f2bf(sv[nt][r]);

        // rescale O accumulator
        #pragma unroll
        for (int nt = 0; nt < 4; ++nt)
            #pragma unroll
            for (int r = 0; r < 4; ++r)
                accO[nt][r] *= alpha_r[r];

        // PV: accO[nt] += P . V
        short8 pa[2];
        #pragma unroll
        for (int kk = 0; kk < 2; ++kk)
            pa[kk] = *(const short8*)&p_s[(wave * 16 + l) * PADK + kk * 32 + g * 8];
        #pragma unroll
        for (int nt = 0; nt < 4; ++nt) {
            #pragma unroll
            for (int kk = 0; kk < 2; ++kk) {
                short8 bv8 = *(const short8*)&vT_s[(nt * 16 + l) * PADK + kk * 32 + g * 8];
                accO[nt] = __builtin_amdgcn_mfma_f32_16x16x32_bf16(pa[kk], bv8, accO[nt], 0, 0, 0);
            }
        }
    }

    // epilogue: Ob = accO / l (bf16)
    float inv[4];
    #pragma unroll
    for (int r = 0; r < 4; ++r) inv[r] = 1.0f / l_run[r];
    #pragma unroll
    for (int nt = 0; nt < 4; ++nt)
        #pragma unroll
        for (int r = 0; r < 4; ++r)
            Ob[(size_t)(b * 512 + i0 + wave * 16 + g * 4 + r) * 512 + h * 64 + nt * 16 + l]
                = f2bf(accO[nt][r] * inv[r]);
}

// ---------------------------------------------------------------------------
// Kernel 3: residual + LayerNorm + exact GELU. One wave per 512-elem row;
// each lane owns 8 contiguous elements (vector loads/stores).
// ---------------------------------------------------------------------------
__global__ __launch_bounds__(256) void ln_gelu_kernel(
    const float* __restrict__ src, const unsigned short* __restrict__ Ob,
    const float* __restrict__ gamma, const float* __restrict__ beta,
    float* __restrict__ out)
{
    const int row  = blockIdx.x * 4 + (threadIdx.x >> 6);
    const int lane = threadIdx.x & 63;
    const int c0   = lane * 8;
    const float* s = &src[(size_t)row * 512 + c0];
    float4 s0 = *(const float4*)(s);
    float4 s1 = *(const float4*)(s + 4);
    unsigned short o8[8];
    *(uint4*)o8 = *(const uint4*)(Ob + (size_t)row * 512 + c0);
    float x[8];
    x[0] = s0.x + bf2f(o8[0]); x[1] = s0.y + bf2f(o8[1]);
    x[2] = s0.z + bf2f(o8[2]); x[3] = s0.w + bf2f(o8[3]);
    x[4] = s1.x + bf2f(o8[4]); x[5] = s1.y + bf2f(o8[5]);
    x[6] = s1.z + bf2f(o8[6]); x[7] = s1.w + bf2f(o8[7]);
    float sum = 0.f;
    #pragma unroll
    for (int e = 0; e < 8; ++e) sum += x[e];
    #pragma unroll
    for (int off = 32; off >= 1; off >>= 1) sum += __shfl_xor(sum, off, 64);
    const float mean = sum * (1.0f / 512.0f);
    float var = 0.f;
    #pragma unroll
    for (int e = 0; e < 8; ++e) { float d = x[e] - mean; var += d * d; }
    #pragma unroll
    for (int off = 32; off >= 1; off >>= 1) var += __shfl_xor(var, off, 64);
    var *= (1.0f / 512.0f);
    const float inv = rsqrtf(var + 1e-5f);
    float4 g0 = *(const float4*)(gamma + c0);
    float4 g1 = *(const float4*)(gamma + c0 + 4);
    float4 b0 = *(const float4*)(beta + c0);
    float4 b1 = *(const float4*)(beta + c0 + 4);
    float gm[8] = {g0.x,g0.y,g0.z,g0.w,g1.x,g1.y,g1.z,g1.w};
    float bt[8] = {b0.x,b0.y,b0.z,b0.w,b1.x,b1.y,b1.z,b1.w};
    float r8[8];
    #pragma unroll
    for (int e = 0; e < 8; ++e) {
        float ln = (x[e] - mean) * inv * gm[e] + bt[e];
        r8[e] = 0.5f * ln * (1.0f + erff(ln * 0.70710678118654752f));
    }
    float* op = &out[(size_t)row * 512 + c0];
    *(float4*)(op)     = make_float4(r8[0], r8[1], r8[2], r8[3]);
    *(float4*)(op + 4) = make_float4(r8[4], r8[5], r8[6], r8[7]);
}

// ---------------------------------------------------------------------------
extern "C" void kernel_launch(void* const* d_in, const int* in_sizes, int n_in,
                              void* d_out, int out_size, void* d_ws, size_t ws_size,
                              hipStream_t stream)
{
    const float* src     = (const float*)d_in[0];
    const int*   seq_len = (const int*)  d_in[1];
    const float* pe      = (const float*)d_in[2];
    const float* Wq      = (const float*)d_in[3];
    const float* bq      = (const float*)d_in[4];
    const float* Wk      = (const float*)d_in[5];
    const float* bk      = (const float*)d_in[6];
    const float* Wv      = (const float*)d_in[7];
    const float* bv      = (const float*)d_in[8];
    const float* Wr      = (const float*)d_in[9];
    const float* br      = (const float*)d_in[10];
    const float* u       = (const float*)d_in[11];
    const float* v       = (const float*)d_in[12];
    const float* gamma   = (const float*)d_in[13];
    const float* beta    = (const float*)d_in[14];
    float* out = (float*)d_out;

    // workspace layout (byte offsets, 16B-aligned)
    char* w = (char*)d_ws;
    unsigned short* QKb = (unsigned short*)(w);              // 4096*1024*2 = 8,388,608
    unsigned short* VTg = (unsigned short*)(w + 8388608);    //  512*4096*2 = 4,194,304
    unsigned short* Rpb = (unsigned short*)(w + 12582912);   // 1024*512*2  = 1,048,576
    unsigned short* Ob  = (unsigned short*)(w + 13631488);   // 4096*512*2  = 4,194,304
    // total ~17.8 MB

    gemm_kernel<<<dim3(416), 256, 0, stream>>>(
        src, pe, Wq, Wk, Wv, Wr, bq, bk, bv, br, QKb, VTg, Rpb);

    attn_kernel<<<dim3(8, NHn, Bn), 256, 0, stream>>>(QKb, VTg, Rpb, u, v, seq_len, Ob);

    ln_gelu_kernel<<<dim3(Bn * Ln / 4), 256, 0, stream>>>(src, Ob, gamma, beta, out);
}

// Round 10
// 133.281 us; speedup vs baseline: 1.0233x; 1.0233x over previous
//
#include <hip/hip_runtime.h>
#include <math.h>

// Problem constants: B=8, L=512, H=512, NH=8, DH=64
#define Bn 8
#define Ln 512
#define Hn 512
#define NHn 8
#define DHn 64

typedef __attribute__((ext_vector_type(8))) short short8;
typedef __attribute__((ext_vector_type(4))) float f32x4;

// fp32 -> bf16 (RNE)
__device__ __forceinline__ unsigned short f2bf(float f) {
    unsigned int u = __float_as_uint(f);
    unsigned int r = (u + 0x7FFFu + ((u >> 16) & 1u)) >> 16;
    return (unsigned short)r;
}
__device__ __forceinline__ float bf2f(unsigned short s) {
    return __uint_as_float(((unsigned int)s) << 16);
}

// ---------------------------------------------------------------------------
// Kernel 0: fp32 -> bf16 conversions (flat grid) + bias concat  [R8-verified]
// ---------------------------------------------------------------------------
__global__ __launch_bounds__(256) void convert_kernel(
    const float* __restrict__ src, const float* __restrict__ pe,
    const float* __restrict__ Wq, const float* __restrict__ Wk,
    const float* __restrict__ Wv, const float* __restrict__ Wr,
    const float* __restrict__ bq, const float* __restrict__ bk,
    const float* __restrict__ bv,
    unsigned short* __restrict__ src_bf, unsigned short* __restrict__ pe_bf,
    unsigned short* __restrict__ Wcat_bf, unsigned short* __restrict__ Wr_bf,
    float* __restrict__ bcat)
{
    const int bid = blockIdx.x;
    const int tid = threadIdx.x;
    const float* in; unsigned short* outp; int base4;
    if (bid < 2048)      { in = src; outp = src_bf;           base4 = bid; }
    else if (bid < 2560) { in = pe;  outp = pe_bf;            base4 = bid - 2048; }
    else if (bid < 2816) { in = Wq;  outp = Wcat_bf;          base4 = bid - 2560; }
    else if (bid < 3072) { in = Wk;  outp = Wcat_bf + 262144; base4 = bid - 2816; }
    else if (bid < 3328) { in = Wv;  outp = Wcat_bf + 524288; base4 = bid - 3072; }
    else if (bid < 3584) { in = Wr;  outp = Wr_bf;            base4 = bid - 3328; }
    else {
        const int idx = (bid - 3584) * 256 + tid;   // 0..1535
        if (idx < 512)            bcat[idx] = bq[idx];
        else if (idx < 1024)      bcat[idx] = bk[idx - 512];
        else if (idx < 1536)      bcat[idx] = bv[idx - 1024];
        return;
    }
    const int i4 = (base4 * 256 + tid) * 4;
    float4 x = *(const float4*)&in[i4];
    ushort4 o;
    o.x = f2bf(x.x); o.y = f2bf(x.y); o.z = f2bf(x.z); o.w = f2bf(x.w);
    *(ushort4*)&outp[i4] = o;
}

// ---------------------------------------------------------------------------
// Kernel 1: bf16 MFMA NT-GEMM, BK=64 (8 K-iterations: half the barriers of
// BK=32), register-prefetch pipeline (tile k+1 loads issue after the staging
// barrier, retire under tile k's ds_reads + 32 MFMAs). LDS rows padded to
// stride 72 (36 dwords = 4 mod 32 banks). 128x128 tile, 256 thr. Flat 416:
//  bid <256 : QK[m][n]   = src.Wcat_n + bcat[n]     (M=4096, N=1024)
//  bid <384 : VT[dv][j'] = Wcat_{1024+dv}.src_j' + bcat[1024+dv]  (swap ->
//             C-layout directly yields V^T [512][4096], coalesced)
//  else     : Rp[m][n]   = pe.Wr_n + br[n]          (M=1024, N=512)
// ---------------------------------------------------------------------------
#define GSTR 72   // LDS row stride (ushorts)
__global__ __launch_bounds__(256) void gemm_kernel(
    const unsigned short* __restrict__ src_bf,
    const unsigned short* __restrict__ Wcat_bf,
    const unsigned short* __restrict__ pe_bf,
    const unsigned short* __restrict__ Wr_bf,
    const float* __restrict__ bcat, const float* __restrict__ br,
    unsigned short* __restrict__ QKb,   // [4096][1024]
    unsigned short* __restrict__ VTg,   // [512][4096]
    unsigned short* __restrict__ Rpb)   // [1024][512]
{
    const int bid = blockIdx.x;
    int mode, m0, n0;
    const unsigned short *A, *B;
    if (bid < 256) {
        mode = 0; n0 = (bid & 7) * 128; m0 = (bid >> 3) * 128;
        A = src_bf + (size_t)m0 * 512;
        B = Wcat_bf + (size_t)n0 * 512;
    } else if (bid < 384) {
        mode = 1; m0 = ((bid - 256) & 3) * 128; n0 = ((bid - 256) >> 2) * 128;
        A = Wcat_bf + (size_t)(1024 + m0) * 512;
        B = src_bf + (size_t)n0 * 512;
    } else {
        mode = 2; n0 = ((bid - 384) & 3) * 128; m0 = ((bid - 384) >> 2) * 128;
        A = pe_bf + (size_t)m0 * 512;
        B = Wr_bf + (size_t)n0 * 512;
    }

    __shared__ unsigned short As[128 * GSTR];   // 18,432 B
    __shared__ unsigned short Bs[128 * GSTR];   // 18,432 B

    const int t = threadIdx.x;
    const int wave = t >> 6, lane = t & 63;
    const int wm = (wave >> 1) * 64;
    const int wn = (wave & 1) * 64;
    const int l = lane & 15, g = lane >> 4;

    f32x4 acc[4][4] = {};

    // staging: thread covers rows {srow, srow+16}, cols [scol, scol+16)
    const int srow = wave * 32 + (lane >> 2);   // 0..15 within wave's 32-row half
    const int scol = (lane & 3) * 16;           // 0,16,32,48
    const unsigned short* Ag = A + (size_t)srow * 512 + scol;
    const unsigned short* Bg = B + (size_t)srow * 512 + scol;
    unsigned short* AsW = &As[srow * GSTR + scol];
    unsigned short* BsW = &Bs[srow * GSTR + scol];

    // prologue prefetch (tile 0): 4 uint4 per buffer per thread
    uint4 a0 = *(const uint4*)(Ag);
    uint4 a1 = *(const uint4*)(Ag + 8);
    uint4 a2 = *(const uint4*)(Ag + 16 * 512);
    uint4 a3 = *(const uint4*)(Ag + 16 * 512 + 8);
    uint4 b0 = *(const uint4*)(Bg);
    uint4 b1 = *(const uint4*)(Bg + 8);
    uint4 b2 = *(const uint4*)(Bg + 16 * 512);
    uint4 b3 = *(const uint4*)(Bg + 16 * 512 + 8);

    for (int k0 = 0; k0 < 512; k0 += 64) {
        __syncthreads();   // prev-iter fragment reads done before overwrite
        *(uint4*)(AsW)                = a0;
        *(uint4*)(AsW + 8)            = a1;
        *(uint4*)(AsW + 16 * GSTR)    = a2;
        *(uint4*)(AsW + 16 * GSTR + 8) = a3;
        *(uint4*)(BsW)                = b0;
        *(uint4*)(BsW + 8)            = b1;
        *(uint4*)(BsW + 16 * GSTR)    = b2;
        *(uint4*)(BsW + 16 * GSTR + 8) = b3;
        __syncthreads();

        // prefetch tile k+1 (retires under the ds_reads + 32 MFMAs below)
        if (k0 + 64 < 512) {
            const int kn = k0 + 64;
            a0 = *(const uint4*)(Ag + kn);
            a1 = *(const uint4*)(Ag + kn + 8);
            a2 = *(const uint4*)(Ag + kn + 16 * 512);
            a3 = *(const uint4*)(Ag + kn + 16 * 512 + 8);
            b0 = *(const uint4*)(Bg + kn);
            b1 = *(const uint4*)(Bg + kn + 8);
            b2 = *(const uint4*)(Bg + kn + 16 * 512);
            b3 = *(const uint4*)(Bg + kn + 16 * 512 + 8);
        }

        #pragma unroll
        for (int kk = 0; kk < 2; ++kk) {
            short8 af[4], bf[4];
            #pragma unroll
            for (int mt = 0; mt < 4; ++mt)
                af[mt] = *(const short8*)&As[(wm + mt * 16 + l) * GSTR + kk * 32 + g * 8];
            #pragma unroll
            for (int nt = 0; nt < 4; ++nt)
                bf[nt] = *(const short8*)&Bs[(wn + nt * 16 + l) * GSTR + kk * 32 + g * 8];
            #pragma unroll
            for (int mt = 0; mt < 4; ++mt)
                #pragma unroll
                for (int nt = 0; nt < 4; ++nt)
                    acc[mt][nt] = __builtin_amdgcn_mfma_f32_16x16x32_bf16(
                        af[mt], bf[nt], acc[mt][nt], 0, 0, 0);
        }
    }

    const int crow = g * 4;
    const int ccol = l;
    if (mode == 0) {
        #pragma unroll
        for (int mt = 0; mt < 4; ++mt)
            #pragma unroll
            for (int nt = 0; nt < 4; ++nt) {
                const int n = n0 + wn + nt * 16 + ccol;
                const float bn = bcat[n];
                #pragma unroll
                for (int r = 0; r < 4; ++r) {
                    const int m = m0 + wm + mt * 16 + crow + r;
                    QKb[(size_t)m * 1024 + n] = f2bf(acc[mt][nt][r] + bn);
                }
            }
    } else if (mode == 1) {
        #pragma unroll
        for (int mt = 0; mt < 4; ++mt)
            #pragma unroll
            for (int nt = 0; nt < 4; ++nt) {
                const int n = n0 + wn + nt * 16 + ccol;      // src row (j')
                #pragma unroll
                for (int r = 0; r < 4; ++r) {
                    const int dv = m0 + wm + mt * 16 + crow + r;  // 0..511
                    VTg[(size_t)dv * 4096 + n] = f2bf(acc[mt][nt][r] + bcat[1024 + dv]);
                }
            }
    } else {
        #pragma unroll
        for (int mt = 0; mt < 4; ++mt)
            #pragma unroll
            for (int nt = 0; nt < 4; ++nt) {
                const int n = n0 + wn + nt * 16 + ccol;
                const float bn = br[n];
                #pragma unroll
                for (int r = 0; r < 4; ++r) {
                    const int m = m0 + wm + mt * 16 + crow + r;
                    Rpb[(size_t)m * 512 + n] = f2bf(acc[mt][nt][r] + bn);
                }
            }
    }
}

// ---------------------------------------------------------------------------
// Kernel 2: fused flash-style rel-pos attention, bf16 MFMA, rolling Bt band,
// register prefetch, masked-tile skip. Block = (b,h,64-row i-tile).  [R8]
// ---------------------------------------------------------------------------
#define PADK 72    // LDS row stride for k/v/rs/p tiles (ushorts)
__global__ __launch_bounds__(256) void attn_kernel(
    const unsigned short* __restrict__ QKb,  // [4096][1024] bf16: q|k
    const unsigned short* __restrict__ VTg,  // [512][4096] bf16 V^T
    const unsigned short* __restrict__ Rpb,  // [1024][512] bf16
    const float* __restrict__ u, const float* __restrict__ v,
    const int* __restrict__ seq_len, unsigned short* __restrict__ Ob)
{
    const int i0 = blockIdx.x * 64;
    const int h  = blockIdx.y;
    const int b  = blockIdx.z;
    const int slen = seq_len[b];
    const int njt = (slen + 63) >> 6;   // 4..8 tiles with any unmasked key

    __shared__ unsigned short k_s [64 * PADK];    // 9216 B
    __shared__ unsigned short vT_s[64 * PADK];    // 9216 B
    __shared__ unsigned short rs_s[64 * PADK];    // 9216 B
    __shared__ unsigned short p_s [64 * PADK];    // 9216 B
    __shared__ unsigned short qrTT[128 * 72];     // 18432 B  QR^T[slot][i]
    // total 55,296 B -> 2 blocks/CU

    const int t = threadIdx.x;
    const int wave = t >> 6, lane = t & 63;
    const int l = lane & 15, g = lane >> 4;

    // ---- per-wave A-fragments qu=q+u, qv=q+v (registers, whole j-loop) ----
    short8 af_qu[2], af_qv[2];
    {
        const unsigned short* qrow =
            QKb + (size_t)(b * 512 + i0 + wave * 16 + l) * 1024 + h * 64;
        #pragma unroll
        for (int kk = 0; kk < 2; ++kk) {
            const int c = kk * 32 + g * 8;
            unsigned short q8[8];
            *(uint4*)q8 = *(const uint4*)(qrow + c);
            float4 u0 = *(const float4*)(u + h * 64 + c);
            float4 u1 = *(const float4*)(u + h * 64 + c + 4);
            float4 v0 = *(const float4*)(v + h * 64 + c);
            float4 v1 = *(const float4*)(v + h * 64 + c + 4);
            float uf[8] = {u0.x,u0.y,u0.z,u0.w,u1.x,u1.y,u1.z,u1.w};
            float vf[8] = {v0.x,v0.y,v0.z,v0.w,v1.x,v1.y,v1.z,v1.w};
            short8 qu, qv;
            #pragma unroll
            for (int e = 0; e < 8; ++e) {
                float qf = bf2f(q8[e]);
                qu[e] = (short)f2bf(qf + uf[e]);
                qv[e] = (short)f2bf(qf + vf[e]);
            }
            af_qu[kk] = qu; af_qv[kk] = qv;
        }
    }

    float m_run[4], l_run[4];
    f32x4 accO[4] = {};
    #pragma unroll
    for (int r = 0; r < 4; ++r) { m_run[r] = -3.0e38f; l_run[r] = 0.f; }

    const int jr = t >> 2, c0 = (t & 3) * 16;   // staging coords

    auto btChunk = [&](int slot0) {
        #pragma unroll
        for (int nt8 = 0; nt8 < 4; ++nt8) {
            f32x4 a = {};
            #pragma unroll
            for (int kk = 0; kk < 2; ++kk) {
                short8 br8 = *(const short8*)&rs_s[(nt8 * 16 + l) * PADK + kk * 32 + g * 8];
                a = __builtin_amdgcn_mfma_f32_16x16x32_bf16(af_qv[kk], br8, a, 0, 0, 0);
            }
            const int sl = slot0 + nt8 * 16 + l;   // slot0 in {0,64} -> sl in [0,127]
            ushort4 w4;
            w4.x = f2bf(a[0]); w4.y = f2bf(a[1]); w4.z = f2bf(a[2]); w4.w = f2bf(a[3]);
            *(ushort4*)(qrTT + sl * 72 + wave * 16 + g * 4) = w4;   // 4 consecutive i
        }
    };

    // ---- prefetch chunk-A rs + tile-0 K/V/rs into registers ----
    const unsigned short* rpA = Rpb + (size_t)(448 - i0 + jr) * 512 + h * 64 + c0;
    uint4 rA0 = *(const uint4*)(rpA);
    uint4 rA1 = *(const uint4*)(rpA + 8);
    const unsigned short* kp0 = QKb + (size_t)(b * 512 + jr) * 1024 + 512 + h * 64 + c0;
    uint4 kc0 = *(const uint4*)(kp0), kc1 = *(const uint4*)(kp0 + 8);
    const unsigned short* vp0 = VTg + (size_t)(h * 64 + jr) * 4096 + b * 512 + c0;
    uint4 vc0 = *(const uint4*)(vp0), vc1 = *(const uint4*)(vp0 + 8);
    const unsigned short* rp0 = Rpb + (size_t)(512 - i0 + jr) * 512 + h * 64 + c0;
    uint4 rc0 = *(const uint4*)(rp0), rc1 = *(const uint4*)(rp0 + 8);

    // ---- chunk A: stage + Bt for bands [448-i0, 512-i0) ----
    *(uint4*)(rs_s + jr * PADK + c0)     = rA0;
    *(uint4*)(rs_s + jr * PADK + c0 + 8) = rA1;
    __syncthreads();
    btChunk((448 - i0) & 127);

    for (int jt = 0; jt < njt; ++jt) {
        const int j0 = jt * 64;
        __syncthreads();   // all prior LDS reads done before restaging

        *(uint4*)(k_s  + jr * PADK + c0)     = kc0;
        *(uint4*)(k_s  + jr * PADK + c0 + 8) = kc1;
        *(uint4*)(vT_s + jr * PADK + c0)     = vc0;
        *(uint4*)(vT_s + jr * PADK + c0 + 8) = vc1;
        *(uint4*)(rs_s + jr * PADK + c0)     = rc0;
        *(uint4*)(rs_s + jr * PADK + c0 + 8) = rc1;
        __syncthreads();

        // prefetch next tile's globals (retire during compute below)
        if (jt + 1 < njt) {
            const unsigned short* kp =
                QKb + (size_t)(b * 512 + j0 + 64 + jr) * 1024 + 512 + h * 64 + c0;
            kc0 = *(const uint4*)(kp); kc1 = *(const uint4*)(kp + 8);
            const unsigned short* vp =
                VTg + (size_t)(h * 64 + jr) * 4096 + b * 512 + j0 + 64 + c0;
            vc0 = *(const uint4*)(vp); vc1 = *(const uint4*)(vp + 8);
            const unsigned short* rp =
                Rpb + (size_t)(j0 + 64 - i0 + 512 + jr) * 512 + h * 64 + c0;
            rc0 = *(const uint4*)(rp); rc1 = *(const uint4*)(rp + 8);
        }

        // Bt: new bands for this tile
        btChunk((j0 - i0 + 512) & 127);

        // A-term: accA[nt] = qu . K^T
        f32x4 accA[4];
        #pragma unroll
        for (int nt = 0; nt < 4; ++nt) {
            f32x4 a = {};
            #pragma unroll
            for (int kk = 0; kk < 2; ++kk) {
                short8 bk8 = *(const short8*)&k_s[(nt * 16 + l) * PADK + kk * 32 + g * 8];
                a = __builtin_amdgcn_mfma_f32_16x16x32_bf16(af_qu[kk], bk8, a, 0, 0, 0);
            }
            accA[nt] = a;
        }

        // gather rolling band + scale + mask
        float sv[4][4];
        #pragma unroll
        for (int nt = 0; nt < 4; ++nt)
            #pragma unroll
            for (int r = 0; r < 4; ++r) {
                const int il = wave * 16 + g * 4 + r;
                const int slot = (j0 + nt * 16 + l - i0 - il + 512) & 127;
                const float qr = bf2f(qrTT[slot * 72 + il]);
                float s = (accA[nt][r] + qr) * 0.125f;
                if (j0 + nt * 16 + l >= slen) s = -1e15f;
                sv[nt][r] = s;
            }

        // online softmax (row r owned by lanes sharing g)
        float alpha_r[4];
        #pragma unroll
        for (int r = 0; r < 4; ++r) {
            float tm = fmaxf(fmaxf(sv[0][r], sv[1][r]), fmaxf(sv[2][r], sv[3][r]));
            tm = fmaxf(tm, __shfl_xor(tm, 1, 64));
            tm = fmaxf(tm, __shfl_xor(tm, 2, 64));
            tm = fmaxf(tm, __shfl_xor(tm, 4, 64));
            tm = fmaxf(tm, __shfl_xor(tm, 8, 64));
            const float mn = fmaxf(m_run[r], tm);
            alpha_r[r] = __expf(m_run[r] - mn);
            m_run[r] = mn;
            float ss = 0.f;
            #pragma unroll
            for (int nt = 0; nt < 4; ++nt) {
                const float pe_ = __expf(sv[nt][r] - mn);
                sv[nt][r] = pe_; ss += pe_;
            }
            ss += __shfl_xor(ss, 1, 64);
            ss += __shfl_xor(ss, 2, 64);
            ss += __shfl_xor(ss, 4, 64);
            ss += __shfl_xor(ss, 8, 64);
            l_run[r] = l_run[r] * alpha_r[r] + ss;
        }

        // write P (wave-private 16-row region)
        #pragma unroll
        for (int nt = 0; nt < 4; ++nt)
            #pragma unroll
            for (int r = 0; r < 4; ++r)
                p_s[(wave * 16 + g * 4 + r) * PADK + nt * 16 + l] = f2bf(sv[nt][r]);

        // rescale O accumulator
        #pragma unroll
        for (int nt = 0; nt < 4; ++nt)
            #pragma unroll
            for (int r = 0; r < 4; ++r)
                accO[nt][r] *= alpha_r[r];

        // PV: accO[nt] += P . V
        short8 pa[2];
        #pragma unroll
        for (int kk = 0; kk < 2; ++kk)
            pa[kk] = *(const short8*)&p_s[(wave * 16 + l) * PADK + kk * 32 + g * 8];
        #pragma unroll
        for (int nt = 0; nt < 4; ++nt) {
            #pragma unroll
            for (int kk = 0; kk < 2; ++kk) {
                short8 bv8 = *(const short8*)&vT_s[(nt * 16 + l) * PADK + kk * 32 + g * 8];
                accO[nt] = __builtin_amdgcn_mfma_f32_16x16x32_bf16(pa[kk], bv8, accO[nt], 0, 0, 0);
            }
        }
    }

    // epilogue: Ob = accO / l (bf16)
    float inv[4];
    #pragma unroll
    for (int r = 0; r < 4; ++r) inv[r] = 1.0f / l_run[r];
    #pragma unroll
    for (int nt = 0; nt < 4; ++nt)
        #pragma unroll
        for (int r = 0; r < 4; ++r)
            Ob[(size_t)(b * 512 + i0 + wave * 16 + g * 4 + r) * 512 + h * 64 + nt * 16 + l]
                = f2bf(accO[nt][r] * inv[r]);
}

// ---------------------------------------------------------------------------
// Kernel 3: residual + LayerNorm + exact GELU. One wave per 512-elem row;
// each lane owns 8 contiguous elements (vector loads/stores).  [R8]
// ---------------------------------------------------------------------------
__global__ __launch_bounds__(256) void ln_gelu_kernel(
    const float* __restrict__ src, const unsigned short* __restrict__ Ob,
    const float* __restrict__ gamma, const float* __restrict__ beta,
    float* __restrict__ out)
{
    const int row  = blockIdx.x * 4 + (threadIdx.x >> 6);
    const int lane = threadIdx.x & 63;
    const int c0   = lane * 8;
    const float* s = &src[(size_t)row * 512 + c0];
    float4 s0 = *(const float4*)(s);
    float4 s1 = *(const float4*)(s + 4);
    unsigned short o8[8];
    *(uint4*)o8 = *(const uint4*)(Ob + (size_t)row * 512 + c0);
    float x[8];
    x[0] = s0.x + bf2f(o8[0]); x[1] = s0.y + bf2f(o8[1]);
    x[2] = s0.z + bf2f(o8[2]); x[3] = s0.w + bf2f(o8[3]);
    x[4] = s1.x + bf2f(o8[4]); x[5] = s1.y + bf2f(o8[5]);
    x[6] = s1.z + bf2f(o8[6]); x[7] = s1.w + bf2f(o8[7]);
    float sum = 0.f;
    #pragma unroll
    for (int e = 0; e < 8; ++e) sum += x[e];
    #pragma unroll
    for (int off = 32; off >= 1; off >>= 1) sum += __shfl_xor(sum, off, 64);
    const float mean = sum * (1.0f / 512.0f);
    float var = 0.f;
    #pragma unroll
    for (int e = 0; e < 8; ++e) { float d = x[e] - mean; var += d * d; }
    #pragma unroll
    for (int off = 32; off >= 1; off >>= 1) var += __shfl_xor(var, off, 64);
    var *= (1.0f / 512.0f);
    const float inv = rsqrtf(var + 1e-5f);
    float4 g0 = *(const float4*)(gamma + c0);
    float4 g1 = *(const float4*)(gamma + c0 + 4);
    float4 b0 = *(const float4*)(beta + c0);
    float4 b1 = *(const float4*)(beta + c0 + 4);
    float gm[8] = {g0.x,g0.y,g0.z,g0.w,g1.x,g1.y,g1.z,g1.w};
    float bt[8] = {b0.x,b0.y,b0.z,b0.w,b1.x,b1.y,b1.z,b1.w};
    float r8[8];
    #pragma unroll
    for (int e = 0; e < 8; ++e) {
        float ln = (x[e] - mean) * inv * gm[e] + bt[e];
        r8[e] = 0.5f * ln * (1.0f + erff(ln * 0.70710678118654752f));
    }
    float* op = &out[(size_t)row * 512 + c0];
    *(float4*)(op)     = make_float4(r8[0], r8[1], r8[2], r8[3]);
    *(float4*)(op + 4) = make_float4(r8[4], r8[5], r8[6], r8[7]);
}

// ---------------------------------------------------------------------------
extern "C" void kernel_launch(void* const* d_in, const int* in_sizes, int n_in,
                              void* d_out, int out_size, void* d_ws, size_t ws_size,
                              hipStream_t stream)
{
    const float* src     = (const float*)d_in[0];
    const int*   seq_len = (const int*)  d_in[1];
    const float* pe      = (const float*)d_in[2];
    const float* Wq      = (const float*)d_in[3];
    const float* bq      = (const float*)d_in[4];
    const float* Wk      = (const float*)d_in[5];
    const float* bk      = (const float*)d_in[6];
    const float* Wv      = (const float*)d_in[7];
    const float* bv      = (const float*)d_in[8];
    const float* Wr      = (const float*)d_in[9];
    const float* br      = (const float*)d_in[10];
    const float* u       = (const float*)d_in[11];
    const float* v       = (const float*)d_in[12];
    const float* gamma   = (const float*)d_in[13];
    const float* beta    = (const float*)d_in[14];
    float* out = (float*)d_out;

    // workspace layout (byte offsets, 16B-aligned)
    char* w = (char*)d_ws;
    unsigned short* QKb     = (unsigned short*)(w);              // 8,388,608
    unsigned short* VTg     = (unsigned short*)(w + 8388608);    // 4,194,304
    unsigned short* Rpb     = (unsigned short*)(w + 12582912);   // 1,048,576
    unsigned short* Ob      = (unsigned short*)(w + 13631488);   // 4,194,304
    unsigned short* src_bf  = (unsigned short*)(w + 17825792);   // 4,194,304
    unsigned short* pe_bf   = (unsigned short*)(w + 22020096);   // 1,048,576
    unsigned short* Wcat_bf = (unsigned short*)(w + 23068672);   // 1,572,864
    unsigned short* Wr_bf   = (unsigned short*)(w + 24641536);   //   524,288
    float*          bcat    = (float*)         (w + 25165824);   //     6,144
    // total ~25.2 MB

    convert_kernel<<<dim3(3590), 256, 0, stream>>>(
        src, pe, Wq, Wk, Wv, Wr, bq, bk, bv,
        src_bf, pe_bf, Wcat_bf, Wr_bf, bcat);

    gemm_kernel<<<dim3(416), 256, 0, stream>>>(
        src_bf, Wcat_bf, pe_bf, Wr_bf, bcat, br, QKb, VTg, Rpb);

    attn_kernel<<<dim3(8, NHn, Bn), 256, 0, stream>>>(QKb, VTg, Rpb, u, v, seq_len, Ob);

    ln_gelu_kernel<<<dim3(Bn * Ln / 4), 256, 0, stream>>>(src, Ob, gamma, beta, out);
}